// Round 1
// baseline (2330.084 us; speedup 1.0000x reference)
//
#include <hip/hip_runtime.h>
#include <hip/hip_bf16.h>

#define N_NODES 50000
#define N_EDGES 640000
#define D 128

// -------- degree count: cnt[dst] += 1 --------
__global__ __launch_bounds__(256) void count_kernel(const int* __restrict__ dst,
                                                    float* __restrict__ cnt) {
    int e = blockIdx.x * 256 + threadIdx.x;
    if (e < N_EDGES) atomicAdd(&cnt[dst[e]], 1.0f);
}

// -------- scatter: agg[dst] += feat[src], float4 per thread --------
__global__ __launch_bounds__(256) void scatter_kernel(const int* __restrict__ src,
                                                      const int* __restrict__ dst,
                                                      const float* __restrict__ feat,
                                                      float* __restrict__ agg) {
    int idx = blockIdx.x * 256 + threadIdx.x;   // E*32 threads exactly
    int e = idx >> 5;
    int j = (idx & 31) * 4;
    int s = src[e];
    int d = dst[e];
    float4 v = *(const float4*)&feat[(size_t)s * D + j];
    float* p = &agg[(size_t)d * D + j];
    atomicAdd(p + 0, v.x);
    atomicAdd(p + 1, v.y);
    atomicAdd(p + 2, v.z);
    atomicAdd(p + 3, v.w);
}

// -------- fused: out = relu( (agg/max(cnt,1)) @ Wl^T + feat @ Wr^T + b ) --------
// Block: 256 threads, tile = 64 nodes x 128 outs. Each thread: 8 nodes x 4 outs.
__global__ __launch_bounds__(256) void sage_linear(const float* __restrict__ feat,
                                                   const float* __restrict__ agg,
                                                   const float* __restrict__ cnt,
                                                   const float* __restrict__ Wl,
                                                   const float* __restrict__ Wr,
                                                   const float* __restrict__ bias,
                                                   float* __restrict__ out) {
    __shared__ float At[16][64];
    __shared__ float Wt[16][128];

    const int tid = threadIdx.x;
    const int tx = tid & 31;        // out-group: cols tx*4 .. tx*4+3
    const int ty = tid >> 5;        // node-group: nodes ty*8 .. ty*8+7
    const int nodeBase = blockIdx.x * 64;

    float acc[8][4];
#pragma unroll
    for (int i = 0; i < 8; ++i)
#pragma unroll
        for (int c = 0; c < 4; ++c) acc[i][c] = 0.0f;

    for (int srcSel = 0; srcSel < 2; ++srcSel) {
        const float* W = srcSel ? Wr : Wl;
        const float* A = srcSel ? feat : agg;
        for (int kc = 0; kc < 128; kc += 16) {
            // ---- stage A tile (transposed): At[k][n] ----
            {
                int n = tid >> 2;            // 0..63
                int kq = (tid & 3) * 4;      // 0,4,8,12
                int node = nodeBase + n;
                float4 v = make_float4(0.f, 0.f, 0.f, 0.f);
                if (node < N_NODES) {
                    v = *(const float4*)&A[(size_t)node * D + kc + kq];
                    if (!srcSel) {
                        float inv = 1.0f / fmaxf(cnt[node], 1.0f);
                        v.x *= inv; v.y *= inv; v.z *= inv; v.w *= inv;
                    }
                }
                At[kq + 0][n] = v.x;
                At[kq + 1][n] = v.y;
                At[kq + 2][n] = v.z;
                At[kq + 3][n] = v.w;
            }
            // ---- stage W tile (transposed): Wt[k][o] = W[o][kc+k] ----
            {
                int o = tid & 127;
                int q = (tid >> 7) * 8;      // 0 or 8
                float4 v0 = *(const float4*)&W[o * D + kc + q];
                float4 v1 = *(const float4*)&W[o * D + kc + q + 4];
                Wt[q + 0][o] = v0.x; Wt[q + 1][o] = v0.y;
                Wt[q + 2][o] = v0.z; Wt[q + 3][o] = v0.w;
                Wt[q + 4][o] = v1.x; Wt[q + 5][o] = v1.y;
                Wt[q + 6][o] = v1.z; Wt[q + 7][o] = v1.w;
            }
            __syncthreads();
#pragma unroll
            for (int k = 0; k < 16; ++k) {
                float4 a01 = *(const float4*)&At[k][ty * 8];
                float4 a23 = *(const float4*)&At[k][ty * 8 + 4];
                float4 bv  = *(const float4*)&Wt[k][tx * 4];
                float av[8] = {a01.x, a01.y, a01.z, a01.w, a23.x, a23.y, a23.z, a23.w};
#pragma unroll
                for (int i = 0; i < 8; ++i) {
                    acc[i][0] += av[i] * bv.x;
                    acc[i][1] += av[i] * bv.y;
                    acc[i][2] += av[i] * bv.z;
                    acc[i][3] += av[i] * bv.w;
                }
            }
            __syncthreads();
        }
    }

    // ---- epilogue: bias + relu + store ----
    float4 bv = *(const float4*)&bias[tx * 4];
#pragma unroll
    for (int i = 0; i < 8; ++i) {
        int node = nodeBase + ty * 8 + i;
        if (node < N_NODES) {
            float4 r;
            r.x = fmaxf(acc[i][0] + bv.x, 0.0f);
            r.y = fmaxf(acc[i][1] + bv.y, 0.0f);
            r.z = fmaxf(acc[i][2] + bv.z, 0.0f);
            r.w = fmaxf(acc[i][3] + bv.w, 0.0f);
            *(float4*)&out[(size_t)node * D + tx * 4] = r;
        }
    }
}

extern "C" void kernel_launch(void* const* d_in, const int* in_sizes, int n_in,
                              void* d_out, int out_size, void* d_ws, size_t ws_size,
                              hipStream_t stream) {
    const float* x   = (const float*)d_in[0];
    const int*   ei  = (const int*)d_in[1];   // jax x64 disabled -> int32
    const int*   src = ei;
    const int*   dst = ei + N_EDGES;
    const float* W1l = (const float*)d_in[2];
    const float* b1  = (const float*)d_in[3];
    const float* W1r = (const float*)d_in[4];
    const float* W2l = (const float*)d_in[5];
    const float* b2  = (const float*)d_in[6];
    const float* W2r = (const float*)d_in[7];
    float* out = (float*)d_out;

    float* h   = (float*)d_ws;                       // N*128
    float* agg = h + (size_t)N_NODES * D;            // N*128
    float* cnt = agg + (size_t)N_NODES * D;          // N

    const int scatterBlocks = (N_EDGES * 32) / 256;  // 80000
    const int gemmBlocks = (N_NODES + 63) / 64;      // 782

    // ---- layer 1 ----
    hipMemsetAsync(agg, 0, sizeof(float) * (size_t)N_NODES * D, stream);
    hipMemsetAsync(cnt, 0, sizeof(float) * (size_t)N_NODES, stream);
    count_kernel<<<(N_EDGES + 255) / 256, 256, 0, stream>>>(dst, cnt);
    scatter_kernel<<<scatterBlocks, 256, 0, stream>>>(src, dst, x, agg);
    sage_linear<<<gemmBlocks, 256, 0, stream>>>(x, agg, cnt, W1l, W1r, b1, h);

    // ---- layer 2 ----
    hipMemsetAsync(agg, 0, sizeof(float) * (size_t)N_NODES * D, stream);
    scatter_kernel<<<scatterBlocks, 256, 0, stream>>>(src, dst, h, agg);
    sage_linear<<<gemmBlocks, 256, 0, stream>>>(h, agg, cnt, W2l, W2r, b2, out);
}

// Round 2
// 402.955 us; speedup vs baseline: 5.7825x; 5.7825x over previous
//
#include <hip/hip_runtime.h>
#include <hip/hip_bf16.h>

#define N_NODES 50000
#define N_EDGES 640000
#define D 128
#define SCAN_T 1024

// -------- histogram: hist[dst]++ stored at row_off[dst+1] --------
__global__ __launch_bounds__(256) void hist_kernel(const int* __restrict__ dst,
                                                   int* __restrict__ row_off) {
    int e = blockIdx.x * 256 + threadIdx.x;
    if (e < N_EDGES) atomicAdd(&row_off[dst[e] + 1], 1);
}

// -------- single-block scan: row_off -> offsets, cursor[i] = row_off[i] --------
__global__ __launch_bounds__(SCAN_T) void scan_kernel(int* __restrict__ row_off,
                                                      int* __restrict__ cursor) {
    __shared__ int part[SCAN_T];
    const int t = threadIdx.x;
    const int C = (N_NODES + SCAN_T - 1) / SCAN_T;   // 49
    const int base = t * C;
    int sum = 0;
    for (int i = 0; i < C; ++i) {
        int idx = base + i;
        if (idx < N_NODES) sum += row_off[idx + 1];
    }
    part[t] = sum;
    __syncthreads();
    // Hillis-Steele inclusive scan over 1024 partials
    for (int off = 1; off < SCAN_T; off <<= 1) {
        int v = part[t];
        int add = (t >= off) ? part[t - off] : 0;
        __syncthreads();
        part[t] = v + add;
        __syncthreads();
    }
    int run = (t == 0) ? 0 : part[t - 1];
    for (int i = 0; i < C; ++i) {
        int idx = base + i;
        if (idx < N_NODES) {
            int v = row_off[idx + 1];
            cursor[idx] = run;        // start offset (exclusive prefix)
            run += v;
            row_off[idx + 1] = run;   // inclusive
        }
    }
    if (t == 0) row_off[0] = 0;
}

// -------- fill: esrc[pos] = src, grouped by dst --------
__global__ __launch_bounds__(256) void fill_kernel(const int* __restrict__ src,
                                                   const int* __restrict__ dst,
                                                   int* __restrict__ cursor,
                                                   int* __restrict__ esrc) {
    int e = blockIdx.x * 256 + threadIdx.x;
    if (e < N_EDGES) {
        int p = atomicAdd(&cursor[dst[e]], 1);
        esrc[p] = src[e];
    }
}

// -------- gather + mean: one wave per node, lane owns 2 floats --------
__global__ __launch_bounds__(256) void gather_mean(const int* __restrict__ row_off,
                                                   const int* __restrict__ esrc,
                                                   const float* __restrict__ feat,
                                                   float* __restrict__ mean) {
    int node = (blockIdx.x * 256 + threadIdx.x) >> 6;
    int lane = threadIdx.x & 63;
    if (node >= N_NODES) return;
    const int beg = row_off[node];
    const int end = row_off[node + 1];
    const int j = lane * 2;
    float ax = 0.0f, ay = 0.0f;
    int i = beg;
    // unroll-by-4 to keep independent loads in flight
    for (; i + 3 < end; i += 4) {
        int s0 = esrc[i], s1 = esrc[i + 1], s2 = esrc[i + 2], s3 = esrc[i + 3];
        float2 v0 = *(const float2*)&feat[(size_t)s0 * D + j];
        float2 v1 = *(const float2*)&feat[(size_t)s1 * D + j];
        float2 v2 = *(const float2*)&feat[(size_t)s2 * D + j];
        float2 v3 = *(const float2*)&feat[(size_t)s3 * D + j];
        ax += v0.x + v1.x + v2.x + v3.x;
        ay += v0.y + v1.y + v2.y + v3.y;
    }
    for (; i < end; ++i) {
        int s = esrc[i];
        float2 v = *(const float2*)&feat[(size_t)s * D + j];
        ax += v.x; ay += v.y;
    }
    float inv = (end > beg) ? 1.0f / (float)(end - beg) : 0.0f;
    float2 r; r.x = ax * inv; r.y = ay * inv;
    *(float2*)&mean[(size_t)node * D + j] = r;
}

// -------- fused: out = relu( mean @ Wl^T + feat @ Wr^T + b ) --------
// Block: 256 threads, tile = 64 nodes x 128 outs. Each thread: 8 nodes x 4 outs.
__global__ __launch_bounds__(256) void sage_linear(const float* __restrict__ feat,
                                                   const float* __restrict__ mean,
                                                   const float* __restrict__ Wl,
                                                   const float* __restrict__ Wr,
                                                   const float* __restrict__ bias,
                                                   float* __restrict__ out) {
    __shared__ float At[16][64];
    __shared__ float Wt[16][128];

    const int tid = threadIdx.x;
    const int tx = tid & 31;        // out-group: cols tx*4 .. tx*4+3
    const int ty = tid >> 5;        // node-group: nodes ty*8 .. ty*8+7
    const int nodeBase = blockIdx.x * 64;

    float acc[8][4];
#pragma unroll
    for (int i = 0; i < 8; ++i)
#pragma unroll
        for (int c = 0; c < 4; ++c) acc[i][c] = 0.0f;

    for (int srcSel = 0; srcSel < 2; ++srcSel) {
        const float* W = srcSel ? Wr : Wl;
        const float* A = srcSel ? feat : mean;
        for (int kc = 0; kc < 128; kc += 16) {
            // ---- stage A tile (transposed): At[k][n] ----
            {
                int n = tid >> 2;            // 0..63
                int kq = (tid & 3) * 4;      // 0,4,8,12
                int node = nodeBase + n;
                float4 v = make_float4(0.f, 0.f, 0.f, 0.f);
                if (node < N_NODES)
                    v = *(const float4*)&A[(size_t)node * D + kc + kq];
                At[kq + 0][n] = v.x;
                At[kq + 1][n] = v.y;
                At[kq + 2][n] = v.z;
                At[kq + 3][n] = v.w;
            }
            // ---- stage W tile (transposed): Wt[k][o] = W[o][kc+k] ----
            {
                int o = tid & 127;
                int q = (tid >> 7) * 8;      // 0 or 8
                float4 v0 = *(const float4*)&W[o * D + kc + q];
                float4 v1 = *(const float4*)&W[o * D + kc + q + 4];
                Wt[q + 0][o] = v0.x; Wt[q + 1][o] = v0.y;
                Wt[q + 2][o] = v0.z; Wt[q + 3][o] = v0.w;
                Wt[q + 4][o] = v1.x; Wt[q + 5][o] = v1.y;
                Wt[q + 6][o] = v1.z; Wt[q + 7][o] = v1.w;
            }
            __syncthreads();
#pragma unroll
            for (int k = 0; k < 16; ++k) {
                float4 a01 = *(const float4*)&At[k][ty * 8];
                float4 a23 = *(const float4*)&At[k][ty * 8 + 4];
                float4 bv  = *(const float4*)&Wt[k][tx * 4];
                float av[8] = {a01.x, a01.y, a01.z, a01.w, a23.x, a23.y, a23.z, a23.w};
#pragma unroll
                for (int i = 0; i < 8; ++i) {
                    acc[i][0] += av[i] * bv.x;
                    acc[i][1] += av[i] * bv.y;
                    acc[i][2] += av[i] * bv.z;
                    acc[i][3] += av[i] * bv.w;
                }
            }
            __syncthreads();
        }
    }

    // ---- epilogue: bias + relu + store ----
    float4 bv = *(const float4*)&bias[tx * 4];
#pragma unroll
    for (int i = 0; i < 8; ++i) {
        int node = nodeBase + ty * 8 + i;
        if (node < N_NODES) {
            float4 r;
            r.x = fmaxf(acc[i][0] + bv.x, 0.0f);
            r.y = fmaxf(acc[i][1] + bv.y, 0.0f);
            r.z = fmaxf(acc[i][2] + bv.z, 0.0f);
            r.w = fmaxf(acc[i][3] + bv.w, 0.0f);
            *(float4*)&out[(size_t)node * D + tx * 4] = r;
        }
    }
}

extern "C" void kernel_launch(void* const* d_in, const int* in_sizes, int n_in,
                              void* d_out, int out_size, void* d_ws, size_t ws_size,
                              hipStream_t stream) {
    const float* x   = (const float*)d_in[0];
    const int*   ei  = (const int*)d_in[1];   // jax x64 disabled -> int32
    const int*   src = ei;
    const int*   dst = ei + N_EDGES;
    const float* W1l = (const float*)d_in[2];
    const float* b1  = (const float*)d_in[3];
    const float* W1r = (const float*)d_in[4];
    const float* W2l = (const float*)d_in[5];
    const float* b2  = (const float*)d_in[6];
    const float* W2r = (const float*)d_in[7];
    float* out = (float*)d_out;

    float* h      = (float*)d_ws;                        // N*128 f32
    float* mean   = h + (size_t)N_NODES * D;             // N*128 f32
    int*   row_off= (int*)(mean + (size_t)N_NODES * D);  // N+1 ints
    int*   cursor = row_off + (N_NODES + 1);             // N ints
    int*   esrc   = cursor + N_NODES;                    // E ints

    const int edgeBlocks = (N_EDGES + 255) / 256;        // 2500
    const int waveBlocks = (N_NODES * 64 + 255) / 256;   // 12500
    const int gemmBlocks = (N_NODES + 63) / 64;          // 782

    // ---- CSR build (once; shared by both layers) ----
    hipMemsetAsync(row_off, 0, sizeof(int) * (N_NODES + 1), stream);
    hist_kernel<<<edgeBlocks, 256, 0, stream>>>(dst, row_off);
    scan_kernel<<<1, SCAN_T, 0, stream>>>(row_off, cursor);
    fill_kernel<<<edgeBlocks, 256, 0, stream>>>(src, dst, cursor, esrc);

    // ---- layer 1 ----
    gather_mean<<<waveBlocks, 256, 0, stream>>>(row_off, esrc, x, mean);
    sage_linear<<<gemmBlocks, 256, 0, stream>>>(x, mean, W1l, W1r, b1, h);

    // ---- layer 2 ----
    gather_mean<<<waveBlocks, 256, 0, stream>>>(row_off, esrc, h, mean);
    sage_linear<<<gemmBlocks, 256, 0, stream>>>(h, mean, W2l, W2r, b2, out);
}

// Round 3
// 293.014 us; speedup vs baseline: 7.9521x; 1.3752x over previous
//
#include <hip/hip_runtime.h>
#include <hip/hip_bf16.h>

#define N_NODES 50000
#define N_EDGES 640000
#define D 128
#define SCAN_BLK 25          // ceil(50000 / 2048)

// -------- histogram: deg[dst]++ --------
__global__ __launch_bounds__(256) void hist_kernel(const int* __restrict__ dst,
                                                   int* __restrict__ deg) {
    int e = blockIdx.x * 256 + threadIdx.x;
    if (e < N_EDGES) atomicAdd(&deg[dst[e]], 1);
}

// -------- scan pass 1: per-block inclusive scan of deg (2048 elems/block) --------
__global__ __launch_bounds__(256) void scan1_kernel(const int* __restrict__ deg,
                                                    int* __restrict__ incl,
                                                    int* __restrict__ blockSum) {
    __shared__ int wsum[4];
    const int t = threadIdx.x;
    const int base = blockIdx.x * 2048 + t * 8;
    int v[8];
    int s = 0;
#pragma unroll
    for (int i = 0; i < 8; ++i) {
        int idx = base + i;
        v[i] = (idx < N_NODES) ? deg[idx] : 0;
        s += v[i];
    }
    const int lane = t & 63;
    const int wid = t >> 6;
    // inclusive wave scan of per-thread sums
    int ps = s;
#pragma unroll
    for (int off = 1; off < 64; off <<= 1) {
        int u = __shfl_up(ps, off, 64);
        if (lane >= off) ps += u;
    }
    if (lane == 63) wsum[wid] = ps;
    __syncthreads();
    int wOff = 0;
    for (int w = 0; w < wid; ++w) wOff += wsum[w];
    int run = wOff + ps - s;          // exclusive prefix for this thread
#pragma unroll
    for (int i = 0; i < 8; ++i) {
        run += v[i];
        int idx = base + i;
        if (idx < N_NODES) incl[idx] = run;
    }
    if (t == 255) blockSum[blockIdx.x] = wOff + ps;
}

// -------- scan pass 2: add block prefix, emit row_off + cursor --------
__global__ __launch_bounds__(256) void scan2_kernel(const int* __restrict__ deg,
                                                    const int* __restrict__ incl,
                                                    const int* __restrict__ blockSum,
                                                    int* __restrict__ row_off,
                                                    int* __restrict__ cursor) {
    const int b = blockIdx.x;
    int off = 0;
    for (int i = 0; i < b; ++i) off += blockSum[i];
    const int t = threadIdx.x;
#pragma unroll
    for (int i = 0; i < 8; ++i) {
        int idx = b * 2048 + i * 256 + t;     // coalesced
        if (idx < N_NODES) {
            int inc = incl[idx] + off;
            row_off[idx + 1] = inc;
            cursor[idx] = inc - deg[idx];
        }
    }
    if (b == 0 && t == 0) row_off[0] = 0;
}

// -------- fill: esrc[pos] = src, grouped by dst --------
__global__ __launch_bounds__(256) void fill_kernel(const int* __restrict__ src,
                                                   const int* __restrict__ dst,
                                                   int* __restrict__ cursor,
                                                   int* __restrict__ esrc) {
    int e = blockIdx.x * 256 + threadIdx.x;
    if (e < N_EDGES) {
        int p = atomicAdd(&cursor[dst[e]], 1);
        esrc[p] = src[e];
    }
}

// -------- gather + mean: one wave per node, lane owns 2 floats --------
__global__ __launch_bounds__(256) void gather_mean(const int* __restrict__ row_off,
                                                   const int* __restrict__ esrc,
                                                   const float* __restrict__ feat,
                                                   float* __restrict__ mean) {
    int node = (blockIdx.x * 256 + threadIdx.x) >> 6;
    int lane = threadIdx.x & 63;
    if (node >= N_NODES) return;
    const int beg = row_off[node];
    const int end = row_off[node + 1];
    const int j = lane * 2;
    float ax = 0.0f, ay = 0.0f;
    int i = beg;
    for (; i + 3 < end; i += 4) {
        int s0 = esrc[i], s1 = esrc[i + 1], s2 = esrc[i + 2], s3 = esrc[i + 3];
        float2 v0 = *(const float2*)&feat[(size_t)s0 * D + j];
        float2 v1 = *(const float2*)&feat[(size_t)s1 * D + j];
        float2 v2 = *(const float2*)&feat[(size_t)s2 * D + j];
        float2 v3 = *(const float2*)&feat[(size_t)s3 * D + j];
        ax += v0.x + v1.x + v2.x + v3.x;
        ay += v0.y + v1.y + v2.y + v3.y;
    }
    for (; i < end; ++i) {
        int s = esrc[i];
        float2 v = *(const float2*)&feat[(size_t)s * D + j];
        ax += v.x; ay += v.y;
    }
    float inv = (end > beg) ? 1.0f / (float)(end - beg) : 0.0f;
    float2 r; r.x = ax * inv; r.y = ay * inv;
    *(float2*)&mean[(size_t)node * D + j] = r;
}

// -------- fused: out = relu( mean @ Wl^T + feat @ Wr^T + b ) --------
__global__ __launch_bounds__(256) void sage_linear(const float* __restrict__ feat,
                                                   const float* __restrict__ mean,
                                                   const float* __restrict__ Wl,
                                                   const float* __restrict__ Wr,
                                                   const float* __restrict__ bias,
                                                   float* __restrict__ out) {
    __shared__ float At[16][64];
    __shared__ float Wt[16][128];

    const int tid = threadIdx.x;
    const int tx = tid & 31;
    const int ty = tid >> 5;
    const int nodeBase = blockIdx.x * 64;

    float acc[8][4];
#pragma unroll
    for (int i = 0; i < 8; ++i)
#pragma unroll
        for (int c = 0; c < 4; ++c) acc[i][c] = 0.0f;

    for (int srcSel = 0; srcSel < 2; ++srcSel) {
        const float* W = srcSel ? Wr : Wl;
        const float* A = srcSel ? feat : mean;
        for (int kc = 0; kc < 128; kc += 16) {
            {
                int n = tid >> 2;
                int kq = (tid & 3) * 4;
                int node = nodeBase + n;
                float4 v = make_float4(0.f, 0.f, 0.f, 0.f);
                if (node < N_NODES)
                    v = *(const float4*)&A[(size_t)node * D + kc + kq];
                At[kq + 0][n] = v.x;
                At[kq + 1][n] = v.y;
                At[kq + 2][n] = v.z;
                At[kq + 3][n] = v.w;
            }
            {
                int o = tid & 127;
                int q = (tid >> 7) * 8;
                float4 v0 = *(const float4*)&W[o * D + kc + q];
                float4 v1 = *(const float4*)&W[o * D + kc + q + 4];
                Wt[q + 0][o] = v0.x; Wt[q + 1][o] = v0.y;
                Wt[q + 2][o] = v0.z; Wt[q + 3][o] = v0.w;
                Wt[q + 4][o] = v1.x; Wt[q + 5][o] = v1.y;
                Wt[q + 6][o] = v1.z; Wt[q + 7][o] = v1.w;
            }
            __syncthreads();
#pragma unroll
            for (int k = 0; k < 16; ++k) {
                float4 a01 = *(const float4*)&At[k][ty * 8];
                float4 a23 = *(const float4*)&At[k][ty * 8 + 4];
                float4 bv  = *(const float4*)&Wt[k][tx * 4];
                float av[8] = {a01.x, a01.y, a01.z, a01.w, a23.x, a23.y, a23.z, a23.w};
#pragma unroll
                for (int i = 0; i < 8; ++i) {
                    acc[i][0] += av[i] * bv.x;
                    acc[i][1] += av[i] * bv.y;
                    acc[i][2] += av[i] * bv.z;
                    acc[i][3] += av[i] * bv.w;
                }
            }
            __syncthreads();
        }
    }

    float4 bv = *(const float4*)&bias[tx * 4];
#pragma unroll
    for (int i = 0; i < 8; ++i) {
        int node = nodeBase + ty * 8 + i;
        if (node < N_NODES) {
            float4 r;
            r.x = fmaxf(acc[i][0] + bv.x, 0.0f);
            r.y = fmaxf(acc[i][1] + bv.y, 0.0f);
            r.z = fmaxf(acc[i][2] + bv.z, 0.0f);
            r.w = fmaxf(acc[i][3] + bv.w, 0.0f);
            *(float4*)&out[(size_t)node * D + tx * 4] = r;
        }
    }
}

extern "C" void kernel_launch(void* const* d_in, const int* in_sizes, int n_in,
                              void* d_out, int out_size, void* d_ws, size_t ws_size,
                              hipStream_t stream) {
    const float* x   = (const float*)d_in[0];
    const int*   ei  = (const int*)d_in[1];   // jax x64 disabled -> int32
    const int*   src = ei;
    const int*   dst = ei + N_EDGES;
    const float* W1l = (const float*)d_in[2];
    const float* b1  = (const float*)d_in[3];
    const float* W1r = (const float*)d_in[4];
    const float* W2l = (const float*)d_in[5];
    const float* b2  = (const float*)d_in[6];
    const float* W2r = (const float*)d_in[7];
    float* out = (float*)d_out;

    float* h       = (float*)d_ws;                         // N*128 f32
    float* mean    = h + (size_t)N_NODES * D;              // N*128 f32
    int*   row_off = (int*)(mean + (size_t)N_NODES * D);   // N+1
    int*   cursor  = row_off + (N_NODES + 1);              // N
    int*   esrc    = cursor + N_NODES;                     // E
    int*   deg     = esrc + N_EDGES;                       // N
    int*   incl    = deg + N_NODES;                        // N
    int*   blockSum= incl + N_NODES;                       // SCAN_BLK

    const int edgeBlocks = (N_EDGES + 255) / 256;          // 2500
    const int waveBlocks = (N_NODES * 64 + 255) / 256;     // 12500
    const int gemmBlocks = (N_NODES + 63) / 64;            // 782

    // ---- CSR build (once; shared by both layers) ----
    hipMemsetAsync(deg, 0, sizeof(int) * N_NODES, stream);
    hist_kernel<<<edgeBlocks, 256, 0, stream>>>(dst, deg);
    scan1_kernel<<<SCAN_BLK, 256, 0, stream>>>(deg, incl, blockSum);
    scan2_kernel<<<SCAN_BLK, 256, 0, stream>>>(deg, incl, blockSum, row_off, cursor);
    fill_kernel<<<edgeBlocks, 256, 0, stream>>>(src, dst, cursor, esrc);

    // ---- layer 1 ----
    gather_mean<<<waveBlocks, 256, 0, stream>>>(row_off, esrc, x, mean);
    sage_linear<<<gemmBlocks, 256, 0, stream>>>(x, mean, W1l, W1r, b1, h);

    // ---- layer 2 ----
    gather_mean<<<waveBlocks, 256, 0, stream>>>(row_off, esrc, h, mean);
    sage_linear<<<gemmBlocks, 256, 0, stream>>>(h, mean, W2l, W2r, b2, out);
}

// Round 4
// 225.463 us; speedup vs baseline: 10.3347x; 1.2996x over previous
//
#include <hip/hip_runtime.h>
#include <hip/hip_bf16.h>

#define N_NODES 50000
#define N_EDGES 640000
#define D 128
#define SCAN_BLK 25          // ceil(50000 / 2048)

typedef __bf16 bf16x8 __attribute__((ext_vector_type(8)));
typedef float f32x4 __attribute__((ext_vector_type(4)));

__device__ __forceinline__ ushort f2bf(float f) {
    __hip_bfloat16 h = __float2bfloat16(f);
    return *(ushort*)&h;
}

// -------- histogram: deg[dst]++ --------
__global__ __launch_bounds__(256) void hist_kernel(const int* __restrict__ dst,
                                                   int* __restrict__ deg) {
    int e = blockIdx.x * 256 + threadIdx.x;
    if (e < N_EDGES) atomicAdd(&deg[dst[e]], 1);
}

// -------- scan pass 1: per-block inclusive scan of deg (2048 elems/block) --------
__global__ __launch_bounds__(256) void scan1_kernel(const int* __restrict__ deg,
                                                    int* __restrict__ incl,
                                                    int* __restrict__ blockSum) {
    __shared__ int wsum[4];
    const int t = threadIdx.x;
    const int base = blockIdx.x * 2048 + t * 8;
    int v[8];
    int s = 0;
#pragma unroll
    for (int i = 0; i < 8; ++i) {
        int idx = base + i;
        v[i] = (idx < N_NODES) ? deg[idx] : 0;
        s += v[i];
    }
    const int lane = t & 63;
    const int wid = t >> 6;
    int ps = s;
#pragma unroll
    for (int off = 1; off < 64; off <<= 1) {
        int u = __shfl_up(ps, off, 64);
        if (lane >= off) ps += u;
    }
    if (lane == 63) wsum[wid] = ps;
    __syncthreads();
    int wOff = 0;
    for (int w = 0; w < wid; ++w) wOff += wsum[w];
    int run = wOff + ps - s;
#pragma unroll
    for (int i = 0; i < 8; ++i) {
        run += v[i];
        int idx = base + i;
        if (idx < N_NODES) incl[idx] = run;
    }
    if (t == 255) blockSum[blockIdx.x] = wOff + ps;
}

// -------- scan pass 2: add block prefix, emit row_off + cursor --------
__global__ __launch_bounds__(256) void scan2_kernel(const int* __restrict__ deg,
                                                    const int* __restrict__ incl,
                                                    const int* __restrict__ blockSum,
                                                    int* __restrict__ row_off,
                                                    int* __restrict__ cursor) {
    const int b = blockIdx.x;
    int off = 0;
    for (int i = 0; i < b; ++i) off += blockSum[i];
    const int t = threadIdx.x;
#pragma unroll
    for (int i = 0; i < 8; ++i) {
        int idx = b * 2048 + i * 256 + t;
        if (idx < N_NODES) {
            int inc = incl[idx] + off;
            row_off[idx + 1] = inc;
            cursor[idx] = inc - deg[idx];
        }
    }
    if (b == 0 && t == 0) row_off[0] = 0;
}

// -------- fill: esrc[pos] = src, grouped by dst --------
__global__ __launch_bounds__(256) void fill_kernel(const int* __restrict__ src,
                                                   const int* __restrict__ dst,
                                                   int* __restrict__ cursor,
                                                   int* __restrict__ esrc) {
    int e = blockIdx.x * 256 + threadIdx.x;
    if (e < N_EDGES) {
        int p = atomicAdd(&cursor[dst[e]], 1);
        esrc[p] = src[e];
    }
}

// -------- gather + mean: one wave per node, lane owns 2 floats --------
__global__ __launch_bounds__(256) void gather_mean(const int* __restrict__ row_off,
                                                   const int* __restrict__ esrc,
                                                   const float* __restrict__ feat,
                                                   float* __restrict__ mean) {
    int node = (blockIdx.x * 256 + threadIdx.x) >> 6;
    int lane = threadIdx.x & 63;
    if (node >= N_NODES) return;
    const int beg = row_off[node];
    const int end = row_off[node + 1];
    const int j = lane * 2;
    float ax = 0.0f, ay = 0.0f;
    int i = beg;
    for (; i + 3 < end; i += 4) {
        int s0 = esrc[i], s1 = esrc[i + 1], s2 = esrc[i + 2], s3 = esrc[i + 3];
        float2 v0 = *(const float2*)&feat[(size_t)s0 * D + j];
        float2 v1 = *(const float2*)&feat[(size_t)s1 * D + j];
        float2 v2 = *(const float2*)&feat[(size_t)s2 * D + j];
        float2 v3 = *(const float2*)&feat[(size_t)s3 * D + j];
        ax += v0.x + v1.x + v2.x + v3.x;
        ay += v0.y + v1.y + v2.y + v3.y;
    }
    for (; i < end; ++i) {
        int s = esrc[i];
        float2 v = *(const float2*)&feat[(size_t)s * D + j];
        ax += v.x; ay += v.y;
    }
    float inv = (end > beg) ? 1.0f / (float)(end - beg) : 0.0f;
    float2 r; r.x = ax * inv; r.y = ay * inv;
    *(float2*)&mean[(size_t)node * D + j] = r;
}

// -------- pack [Wl|Wr] (both [128,128] row-major, out x in) into bf16 [128][256] --------
__global__ __launch_bounds__(256) void convw_kernel(const float* __restrict__ W1l,
                                                    const float* __restrict__ W1r,
                                                    const float* __restrict__ W2l,
                                                    const float* __restrict__ W2r,
                                                    ushort* __restrict__ Wb1,
                                                    ushort* __restrict__ Wb2) {
    int i = blockIdx.x * 256 + threadIdx.x;
    if (i < 32768) {
        int n = i >> 8, k = i & 255;
        float v = (k < 128) ? W1l[n * 128 + k] : W1r[n * 128 + (k - 128)];
        Wb1[i] = f2bf(v);
    } else if (i < 65536) {
        int j = i - 32768;
        int n = j >> 8, k = j & 255;
        float v = (k < 128) ? W2l[n * 128 + k] : W2r[n * 128 + (k - 128)];
        Wb2[j] = f2bf(v);
    }
}

// -------- fused MFMA: out = relu( [mean|feat](bf16) @ Wb^T + b ) --------
// Block: 256 threads (4 waves), tile 64 nodes x 128 outs, K = 256.
// Wave w owns cols [w*32, w*32+32) x all 64 rows: acc[4 mfrag][2 nfrag].
// A staged in LDS as bf16, XOR-swizzled: byte ^= (row&7)<<4.
__global__ __launch_bounds__(256) void sage_mfma(const float* __restrict__ feat,
                                                 const float* __restrict__ mean,
                                                 const ushort* __restrict__ Wb,
                                                 const float* __restrict__ bias,
                                                 float* __restrict__ out) {
    __shared__ __align__(16) char As[64 * 512];   // 64 rows x 256 bf16, swizzled

    const int tid = threadIdx.x;
    const int nodeBase = blockIdx.x * 64;

    // ---- stage: fp32 -> bf16, swizzled LDS write ----
    {
        const int row = tid >> 2;          // 0..63
        const int q = tid & 3;             // 64-col quarter
        const int node = nodeBase + row;
        const bool valid = node < N_NODES;
        const float* srcp = (q < 2) ? (mean + (size_t)node * D + q * 64)
                                    : (feat + (size_t)node * D + (q - 2) * 64);
        const int swz = (row & 7) << 4;
#pragma unroll
        for (int c = 0; c < 8; ++c) {      // 8 chunks of 8 floats
            float4 u0 = make_float4(0.f, 0.f, 0.f, 0.f);
            float4 u1 = make_float4(0.f, 0.f, 0.f, 0.f);
            if (valid) {
                u0 = *(const float4*)(srcp + c * 8);
                u1 = *(const float4*)(srcp + c * 8 + 4);
            }
            union { ushort u[8]; uint4 v; } p;
            p.u[0] = f2bf(u0.x); p.u[1] = f2bf(u0.y);
            p.u[2] = f2bf(u0.z); p.u[3] = f2bf(u0.w);
            p.u[4] = f2bf(u1.x); p.u[5] = f2bf(u1.y);
            p.u[6] = f2bf(u1.z); p.u[7] = f2bf(u1.w);
            int colb = (q * 64 + c * 8) * 2;               // byte col
            *(uint4*)(As + row * 512 + (colb ^ swz)) = p.v;
        }
    }
    __syncthreads();

    // ---- MFMA main loop ----
    const int lane = tid & 63;
    const int w = tid >> 6;            // wave id: col slice w*32
    const int l15 = lane & 15;
    const int lg = lane >> 4;          // k-group
    const int swz = (l15 & 7) << 4;

    f32x4 acc[4][2];
#pragma unroll
    for (int m = 0; m < 4; ++m) {
        acc[m][0] = (f32x4)(0.0f);
        acc[m][1] = (f32x4)(0.0f);
    }

    const ushort* WA = Wb + (size_t)(w * 32 + l15) * 256 + lg * 8;
    const ushort* WB = WA + 16 * 256;

#pragma unroll
    for (int t = 0; t < 8; ++t) {      // k0 = t*32
        bf16x8 b0 = *(const bf16x8*)(WA + t * 32);
        bf16x8 b1 = *(const bf16x8*)(WB + t * 32);
        const int kb = t * 64 + lg * 16;                   // byte col base
#pragma unroll
        for (int m = 0; m < 4; ++m) {
            bf16x8 a = *(const bf16x8*)(As + (m * 16 + l15) * 512 + (kb ^ swz));
            acc[m][0] = __builtin_amdgcn_mfma_f32_16x16x32_bf16(a, b0, acc[m][0], 0, 0, 0);
            acc[m][1] = __builtin_amdgcn_mfma_f32_16x16x32_bf16(a, b1, acc[m][1], 0, 0, 0);
        }
    }

    // ---- epilogue: bias + relu + store ----
    const int c0 = w * 32 + l15;
    const float bv0 = bias[c0];
    const float bv1 = bias[c0 + 16];
#pragma unroll
    for (int m = 0; m < 4; ++m) {
#pragma unroll
        for (int j = 0; j < 4; ++j) {
            int node = nodeBase + m * 16 + lg * 4 + j;
            if (node < N_NODES) {
                out[(size_t)node * D + c0]      = fmaxf(acc[m][0][j] + bv0, 0.0f);
                out[(size_t)node * D + c0 + 16] = fmaxf(acc[m][1][j] + bv1, 0.0f);
            }
        }
    }
}

extern "C" void kernel_launch(void* const* d_in, const int* in_sizes, int n_in,
                              void* d_out, int out_size, void* d_ws, size_t ws_size,
                              hipStream_t stream) {
    const float* x   = (const float*)d_in[0];
    const int*   ei  = (const int*)d_in[1];   // jax x64 disabled -> int32
    const int*   src = ei;
    const int*   dst = ei + N_EDGES;
    const float* W1l = (const float*)d_in[2];
    const float* b1  = (const float*)d_in[3];
    const float* W1r = (const float*)d_in[4];
    const float* W2l = (const float*)d_in[5];
    const float* b2  = (const float*)d_in[6];
    const float* W2r = (const float*)d_in[7];
    float* out = (float*)d_out;

    float* h       = (float*)d_ws;                         // N*128 f32
    float* mean    = h + (size_t)N_NODES * D;              // N*128 f32
    int*   row_off = (int*)(mean + (size_t)N_NODES * D);   // N+1
    int*   cursor  = row_off + (N_NODES + 1);              // N
    int*   esrc    = cursor + N_NODES;                     // E
    int*   deg     = esrc + N_EDGES;                       // N
    int*   incl    = deg + N_NODES;                        // N
    int*   blockSum= incl + N_NODES;                       // SCAN_BLK
    ushort* Wb1    = (ushort*)(blockSum + SCAN_BLK);       // 128*256 bf16
    ushort* Wb2    = Wb1 + 128 * 256;                      // 128*256 bf16

    const int edgeBlocks = (N_EDGES + 255) / 256;          // 2500
    const int waveBlocks = (N_NODES * 64 + 255) / 256;     // 12500
    const int gemmBlocks = (N_NODES + 63) / 64;            // 782

    // ---- weight pack + CSR build (once; shared by both layers) ----
    convw_kernel<<<256, 256, 0, stream>>>(W1l, W1r, W2l, W2r, Wb1, Wb2);
    hipMemsetAsync(deg, 0, sizeof(int) * N_NODES, stream);
    hist_kernel<<<edgeBlocks, 256, 0, stream>>>(dst, deg);
    scan1_kernel<<<SCAN_BLK, 256, 0, stream>>>(deg, incl, blockSum);
    scan2_kernel<<<SCAN_BLK, 256, 0, stream>>>(deg, incl, blockSum, row_off, cursor);
    fill_kernel<<<edgeBlocks, 256, 0, stream>>>(src, dst, cursor, esrc);

    // ---- layer 1 ----
    gather_mean<<<waveBlocks, 256, 0, stream>>>(row_off, esrc, x, mean);
    sage_mfma<<<gemmBlocks, 256, 0, stream>>>(x, mean, Wb1, b1, h);

    // ---- layer 2 ----
    gather_mean<<<waveBlocks, 256, 0, stream>>>(row_off, esrc, h, mean);
    sage_mfma<<<gemmBlocks, 256, 0, stream>>>(h, mean, Wb2, b2, out);
}

// Round 5
// 199.756 us; speedup vs baseline: 11.6647x; 1.1287x over previous
//
#include <hip/hip_runtime.h>
#include <hip/hip_bf16.h>

#define N_NODES 50000
#define N_EDGES 640000
#define D 128
#define SCAN_BLK 25          // ceil(50000 / 2048)

typedef __bf16 bf16x8 __attribute__((ext_vector_type(8)));
typedef float f32x4 __attribute__((ext_vector_type(4)));

__device__ __forceinline__ ushort f2bf(float f) {
    __hip_bfloat16 h = __float2bfloat16(f);
    return *(ushort*)&h;
}
__device__ __forceinline__ float bflo(uint u) { return __uint_as_float(u << 16); }
__device__ __forceinline__ float bfhi(uint u) { return __uint_as_float(u & 0xffff0000u); }

// -------- convert x (fp32) -> xb (bf16), 8 elems/thread --------
__global__ __launch_bounds__(256) void convx_kernel(const float* __restrict__ x,
                                                    ushort* __restrict__ xb) {
    int i = blockIdx.x * 256 + threadIdx.x;   // 800000 threads exactly
    const float4 u0 = *(const float4*)&x[i * 8];
    const float4 u1 = *(const float4*)&x[i * 8 + 4];
    union { ushort u[8]; uint4 v; } p;
    p.u[0] = f2bf(u0.x); p.u[1] = f2bf(u0.y); p.u[2] = f2bf(u0.z); p.u[3] = f2bf(u0.w);
    p.u[4] = f2bf(u1.x); p.u[5] = f2bf(u1.y); p.u[6] = f2bf(u1.z); p.u[7] = f2bf(u1.w);
    *(uint4*)&xb[i * 8] = p.v;
}

// -------- histogram: deg[dst]++ --------
__global__ __launch_bounds__(256) void hist_kernel(const int* __restrict__ dst,
                                                   int* __restrict__ deg) {
    int e = blockIdx.x * 256 + threadIdx.x;
    if (e < N_EDGES) atomicAdd(&deg[dst[e]], 1);
}

// -------- scan pass 1: per-block inclusive scan of deg (2048 elems/block) --------
__global__ __launch_bounds__(256) void scan1_kernel(const int* __restrict__ deg,
                                                    int* __restrict__ incl,
                                                    int* __restrict__ blockSum) {
    __shared__ int wsum[4];
    const int t = threadIdx.x;
    const int base = blockIdx.x * 2048 + t * 8;
    int v[8];
    int s = 0;
#pragma unroll
    for (int i = 0; i < 8; ++i) {
        int idx = base + i;
        v[i] = (idx < N_NODES) ? deg[idx] : 0;
        s += v[i];
    }
    const int lane = t & 63;
    const int wid = t >> 6;
    int ps = s;
#pragma unroll
    for (int off = 1; off < 64; off <<= 1) {
        int u = __shfl_up(ps, off, 64);
        if (lane >= off) ps += u;
    }
    if (lane == 63) wsum[wid] = ps;
    __syncthreads();
    int wOff = 0;
    for (int w = 0; w < wid; ++w) wOff += wsum[w];
    int run = wOff + ps - s;
#pragma unroll
    for (int i = 0; i < 8; ++i) {
        run += v[i];
        int idx = base + i;
        if (idx < N_NODES) incl[idx] = run;
    }
    if (t == 255) blockSum[blockIdx.x] = wOff + ps;
}

// -------- scan pass 2: add block prefix, emit row_off + cursor --------
__global__ __launch_bounds__(256) void scan2_kernel(const int* __restrict__ deg,
                                                    const int* __restrict__ incl,
                                                    const int* __restrict__ blockSum,
                                                    int* __restrict__ row_off,
                                                    int* __restrict__ cursor) {
    const int b = blockIdx.x;
    int off = 0;
    for (int i = 0; i < b; ++i) off += blockSum[i];
    const int t = threadIdx.x;
#pragma unroll
    for (int i = 0; i < 8; ++i) {
        int idx = b * 2048 + i * 256 + t;
        if (idx < N_NODES) {
            int inc = incl[idx] + off;
            row_off[idx + 1] = inc;
            cursor[idx] = inc - deg[idx];
        }
    }
    if (b == 0 && t == 0) row_off[0] = 0;
}

// -------- fill: esrc[pos] = src, grouped by dst --------
__global__ __launch_bounds__(256) void fill_kernel(const int* __restrict__ src,
                                                   const int* __restrict__ dst,
                                                   int* __restrict__ cursor,
                                                   int* __restrict__ esrc) {
    int e = blockIdx.x * 256 + threadIdx.x;
    if (e < N_EDGES) {
        int p = atomicAdd(&cursor[dst[e]], 1);
        esrc[p] = src[e];
    }
}

// -------- gather + mean (bf16 in, bf16 out): one wave per node, lane owns 2 elems --------
__global__ __launch_bounds__(256) void gather_mean(const int* __restrict__ row_off,
                                                   const int* __restrict__ esrc,
                                                   const ushort* __restrict__ feat,
                                                   ushort* __restrict__ mean) {
    int node = (blockIdx.x * 256 + threadIdx.x) >> 6;
    int lane = threadIdx.x & 63;
    if (node >= N_NODES) return;
    const int beg = row_off[node];
    const int end = row_off[node + 1];
    const size_t jb = (size_t)lane * 4;     // byte offset within 256B row
    const char* fb = (const char*)feat;
    float ax = 0.0f, ay = 0.0f;
    int i = beg;
    for (; i + 3 < end; i += 4) {
        int s0 = esrc[i], s1 = esrc[i + 1], s2 = esrc[i + 2], s3 = esrc[i + 3];
        uint u0 = *(const uint*)(fb + ((size_t)s0 << 8) + jb);
        uint u1 = *(const uint*)(fb + ((size_t)s1 << 8) + jb);
        uint u2 = *(const uint*)(fb + ((size_t)s2 << 8) + jb);
        uint u3 = *(const uint*)(fb + ((size_t)s3 << 8) + jb);
        ax += bflo(u0) + bflo(u1) + bflo(u2) + bflo(u3);
        ay += bfhi(u0) + bfhi(u1) + bfhi(u2) + bfhi(u3);
    }
    for (; i < end; ++i) {
        uint u = *(const uint*)(fb + ((size_t)esrc[i] << 8) + jb);
        ax += bflo(u); ay += bfhi(u);
    }
    float inv = (end > beg) ? 1.0f / (float)(end - beg) : 0.0f;
    union { ushort u[2]; uint v; } r;
    r.u[0] = f2bf(ax * inv);
    r.u[1] = f2bf(ay * inv);
    *(uint*)((char*)mean + ((size_t)node << 8) + jb) = r.v;
}

// -------- pack [Wl|Wr] (both [128,128] row-major, out x in) into bf16 [128][256] --------
__global__ __launch_bounds__(256) void convw_kernel(const float* __restrict__ W1l,
                                                    const float* __restrict__ W1r,
                                                    const float* __restrict__ W2l,
                                                    const float* __restrict__ W2r,
                                                    ushort* __restrict__ Wb1,
                                                    ushort* __restrict__ Wb2) {
    int i = blockIdx.x * 256 + threadIdx.x;
    if (i < 32768) {
        int n = i >> 8, k = i & 255;
        float v = (k < 128) ? W1l[n * 128 + k] : W1r[n * 128 + (k - 128)];
        Wb1[i] = f2bf(v);
    } else if (i < 65536) {
        int j = i - 32768;
        int n = j >> 8, k = j & 255;
        float v = (k < 128) ? W2l[n * 128 + k] : W2r[n * 128 + (k - 128)];
        Wb2[j] = f2bf(v);
    }
}

// -------- fused MFMA: out = relu( [mean|feat](bf16) @ Wb^T + b ) --------
// Block: 256 threads (4 waves), tile 64 nodes x 128 outs, K = 256.
// Wave w owns cols [w*32, w*32+32): acc[4 mfrag][2 nfrag].
// A staged in LDS bf16, XOR-swizzled: byte ^= (row&7)<<4.
template <int OUT_BF16>
__global__ __launch_bounds__(256) void sage_mfma(const ushort* __restrict__ feat,
                                                 const ushort* __restrict__ mean,
                                                 const ushort* __restrict__ Wb,
                                                 const float* __restrict__ bias,
                                                 void* __restrict__ outv) {
    __shared__ __align__(16) char As[64 * 512];   // 64 rows x 256 bf16, swizzled

    const int tid = threadIdx.x;
    const int nodeBase = blockIdx.x * 64;

    // ---- stage: bf16 rows -> swizzled LDS ----
    {
        const int row = tid >> 2;          // 0..63
        const int q = tid & 3;             // 128-byte quarter of the 512B row
        const int node = nodeBase + row;
        const bool valid = node < N_NODES;
        const ushort* srcp = (q < 2) ? (mean + (size_t)node * D + q * 64)
                                     : (feat + (size_t)node * D + (q - 2) * 64);
        const int swz = (row & 7) << 4;
#pragma unroll
        for (int c = 0; c < 8; ++c) {      // 8 chunks of 16 B
            uint4 v = make_uint4(0u, 0u, 0u, 0u);
            if (valid) v = *(const uint4*)(srcp + c * 8);
            int colb = q * 128 + c * 16;   // byte col
            *(uint4*)(As + row * 512 + (colb ^ swz)) = v;
        }
    }
    __syncthreads();

    // ---- MFMA main loop ----
    const int lane = tid & 63;
    const int w = tid >> 6;            // wave id: col slice w*32
    const int l15 = lane & 15;
    const int lg = lane >> 4;          // k-group
    const int swz = (l15 & 7) << 4;

    f32x4 acc[4][2];
#pragma unroll
    for (int m = 0; m < 4; ++m) {
        acc[m][0] = (f32x4)(0.0f);
        acc[m][1] = (f32x4)(0.0f);
    }

    const ushort* WA = Wb + (size_t)(w * 32 + l15) * 256 + lg * 8;
    const ushort* WB = WA + 16 * 256;

#pragma unroll
    for (int t = 0; t < 8; ++t) {      // k0 = t*32
        bf16x8 b0 = *(const bf16x8*)(WA + t * 32);
        bf16x8 b1 = *(const bf16x8*)(WB + t * 32);
        const int kb = t * 64 + lg * 16;                   // byte col base
#pragma unroll
        for (int m = 0; m < 4; ++m) {
            bf16x8 a = *(const bf16x8*)(As + (m * 16 + l15) * 512 + (kb ^ swz));
            acc[m][0] = __builtin_amdgcn_mfma_f32_16x16x32_bf16(a, b0, acc[m][0], 0, 0, 0);
            acc[m][1] = __builtin_amdgcn_mfma_f32_16x16x32_bf16(a, b1, acc[m][1], 0, 0, 0);
        }
    }

    // ---- epilogue: bias + relu + store ----
    const int c0 = w * 32 + l15;
    const float bv0 = bias[c0];
    const float bv1 = bias[c0 + 16];
#pragma unroll
    for (int m = 0; m < 4; ++m) {
#pragma unroll
        for (int j = 0; j < 4; ++j) {
            int node = nodeBase + m * 16 + lg * 4 + j;
            if (node < N_NODES) {
                float r0 = fmaxf(acc[m][0][j] + bv0, 0.0f);
                float r1 = fmaxf(acc[m][1][j] + bv1, 0.0f);
                if (OUT_BF16) {
                    ushort* out = (ushort*)outv;
                    out[(size_t)node * D + c0]      = f2bf(r0);
                    out[(size_t)node * D + c0 + 16] = f2bf(r1);
                } else {
                    float* out = (float*)outv;
                    out[(size_t)node * D + c0]      = r0;
                    out[(size_t)node * D + c0 + 16] = r1;
                }
            }
        }
    }
}

extern "C" void kernel_launch(void* const* d_in, const int* in_sizes, int n_in,
                              void* d_out, int out_size, void* d_ws, size_t ws_size,
                              hipStream_t stream) {
    const float* x   = (const float*)d_in[0];
    const int*   ei  = (const int*)d_in[1];   // jax x64 disabled -> int32
    const int*   src = ei;
    const int*   dst = ei + N_EDGES;
    const float* W1l = (const float*)d_in[2];
    const float* b1  = (const float*)d_in[3];
    const float* W1r = (const float*)d_in[4];
    const float* W2l = (const float*)d_in[5];
    const float* b2  = (const float*)d_in[6];
    const float* W2r = (const float*)d_in[7];
    float* out = (float*)d_out;

    ushort* xb     = (ushort*)d_ws;                        // N*D bf16
    ushort* hb     = xb + (size_t)N_NODES * D;             // N*D bf16
    ushort* meanb  = hb + (size_t)N_NODES * D;             // N*D bf16
    int*   row_off = (int*)(meanb + (size_t)N_NODES * D);  // N+1
    int*   cursor  = row_off + (N_NODES + 1);              // N
    int*   esrc    = cursor + N_NODES;                     // E
    int*   deg     = esrc + N_EDGES;                       // N
    int*   incl    = deg + N_NODES;                        // N
    int*   blockSum= incl + N_NODES;                       // SCAN_BLK
    ushort* Wb1    = (ushort*)(blockSum + SCAN_BLK);       // 128*256 bf16
    ushort* Wb2    = Wb1 + 128 * 256;                      // 128*256 bf16

    const int edgeBlocks = (N_EDGES + 255) / 256;          // 2500
    const int waveBlocks = (N_NODES * 64 + 255) / 256;     // 12500
    const int gemmBlocks = (N_NODES + 63) / 64;            // 782
    const int convBlocks = (N_NODES * D / 8) / 256;        // 3125 exact

    // ---- converts + CSR build (once; shared by both layers) ----
    convw_kernel<<<256, 256, 0, stream>>>(W1l, W1r, W2l, W2r, Wb1, Wb2);
    convx_kernel<<<convBlocks, 256, 0, stream>>>(x, xb);
    hipMemsetAsync(deg, 0, sizeof(int) * N_NODES, stream);
    hist_kernel<<<edgeBlocks, 256, 0, stream>>>(dst, deg);
    scan1_kernel<<<SCAN_BLK, 256, 0, stream>>>(deg, incl, blockSum);
    scan2_kernel<<<SCAN_BLK, 256, 0, stream>>>(deg, incl, blockSum, row_off, cursor);
    fill_kernel<<<edgeBlocks, 256, 0, stream>>>(src, dst, cursor, esrc);

    // ---- layer 1 ----
    gather_mean<<<waveBlocks, 256, 0, stream>>>(row_off, esrc, xb, meanb);
    sage_mfma<1><<<gemmBlocks, 256, 0, stream>>>(xb, meanb, Wb1, b1, hb);

    // ---- layer 2 ----
    gather_mean<<<waveBlocks, 256, 0, stream>>>(row_off, esrc, hb, meanb);
    sage_mfma<0><<<gemmBlocks, 256, 0, stream>>>(hb, meanb, Wb2, b2, out);
}

// Round 6
// 176.512 us; speedup vs baseline: 13.2007x; 1.1317x over previous
//
#include <hip/hip_runtime.h>
#include <hip/hip_bf16.h>

#define N_NODES 50000
#define N_EDGES 640000
#define D 128
#define SCAN_BLK 25          // ceil(50000 / 2048)

typedef __bf16 bf16x8 __attribute__((ext_vector_type(8)));
typedef float f32x4 __attribute__((ext_vector_type(4)));

__device__ __forceinline__ ushort f2bf(float f) {
    __hip_bfloat16 h = __float2bfloat16(f);
    return *(ushort*)&h;
}
__device__ __forceinline__ float bflo(uint u) { return __uint_as_float(u << 16); }
__device__ __forceinline__ float bfhi(uint u) { return __uint_as_float(u & 0xffff0000u); }

// -------- prep: convx + convw + deg zero, fused (one launch) --------
// blocks [0,3125): x->xb bf16 (8 elems/thread)
// blocks [3125,3381): pack W1/W2 into Wb1/Wb2
// blocks [3381,3577): deg = 0
__global__ __launch_bounds__(256) void prep_kernel(const float* __restrict__ x,
                                                   const float* __restrict__ W1l,
                                                   const float* __restrict__ W1r,
                                                   const float* __restrict__ W2l,
                                                   const float* __restrict__ W2r,
                                                   ushort* __restrict__ xb,
                                                   ushort* __restrict__ Wb1,
                                                   ushort* __restrict__ Wb2,
                                                   int* __restrict__ deg) {
    const int b = blockIdx.x;
    const int tid = threadIdx.x;
    if (b < 3125) {
        int i = b * 256 + tid;
        const float4 u0 = *(const float4*)&x[i * 8];
        const float4 u1 = *(const float4*)&x[i * 8 + 4];
        union { ushort u[8]; uint4 v; } p;
        p.u[0] = f2bf(u0.x); p.u[1] = f2bf(u0.y); p.u[2] = f2bf(u0.z); p.u[3] = f2bf(u0.w);
        p.u[4] = f2bf(u1.x); p.u[5] = f2bf(u1.y); p.u[6] = f2bf(u1.z); p.u[7] = f2bf(u1.w);
        *(uint4*)&xb[i * 8] = p.v;
    } else if (b < 3381) {
        int i = (b - 3125) * 256 + tid;     // [0, 65536)
        if (i < 32768) {
            int n = i >> 8, k = i & 255;
            float v = (k < 128) ? W1l[n * 128 + k] : W1r[n * 128 + (k - 128)];
            Wb1[i] = f2bf(v);
        } else {
            int j = i - 32768;
            int n = j >> 8, k = j & 255;
            float v = (k < 128) ? W2l[n * 128 + k] : W2r[n * 128 + (k - 128)];
            Wb2[j] = f2bf(v);
        }
    } else {
        int i = (b - 3381) * 256 + tid;
        if (i < N_NODES) deg[i] = 0;
    }
}

// -------- histogram: deg[dst]++, 4 edges/thread (pipelined atomics) --------
__global__ __launch_bounds__(256) void hist_kernel(const int* __restrict__ dst,
                                                   int* __restrict__ deg) {
    const int base = blockIdx.x * 1024 + threadIdx.x;
    int d0 = dst[base];
    int d1 = dst[base + 256];
    int d2 = dst[base + 512];
    int d3 = dst[base + 768];
    atomicAdd(&deg[d0], 1);
    atomicAdd(&deg[d1], 1);
    atomicAdd(&deg[d2], 1);
    atomicAdd(&deg[d3], 1);
}

// -------- scan pass 1: per-block inclusive scan of deg (2048 elems/block) --------
__global__ __launch_bounds__(256) void scan1_kernel(const int* __restrict__ deg,
                                                    int* __restrict__ incl,
                                                    int* __restrict__ blockSum) {
    __shared__ int wsum[4];
    const int t = threadIdx.x;
    const int base = blockIdx.x * 2048 + t * 8;
    int v[8];
    int s = 0;
#pragma unroll
    for (int i = 0; i < 8; ++i) {
        int idx = base + i;
        v[i] = (idx < N_NODES) ? deg[idx] : 0;
        s += v[i];
    }
    const int lane = t & 63;
    const int wid = t >> 6;
    int ps = s;
#pragma unroll
    for (int off = 1; off < 64; off <<= 1) {
        int u = __shfl_up(ps, off, 64);
        if (lane >= off) ps += u;
    }
    if (lane == 63) wsum[wid] = ps;
    __syncthreads();
    int wOff = 0;
    for (int w = 0; w < wid; ++w) wOff += wsum[w];
    int run = wOff + ps - s;
#pragma unroll
    for (int i = 0; i < 8; ++i) {
        run += v[i];
        int idx = base + i;
        if (idx < N_NODES) incl[idx] = run;
    }
    if (t == 255) blockSum[blockIdx.x] = wOff + ps;
}

// -------- scan pass 2: add block prefix, emit row_off + cursor --------
__global__ __launch_bounds__(256) void scan2_kernel(const int* __restrict__ deg,
                                                    const int* __restrict__ incl,
                                                    const int* __restrict__ blockSum,
                                                    int* __restrict__ row_off,
                                                    int* __restrict__ cursor) {
    const int b = blockIdx.x;
    int off = 0;
    for (int i = 0; i < b; ++i) off += blockSum[i];
    const int t = threadIdx.x;
#pragma unroll
    for (int i = 0; i < 8; ++i) {
        int idx = b * 2048 + i * 256 + t;
        if (idx < N_NODES) {
            int inc = incl[idx] + off;
            row_off[idx + 1] = inc;
            cursor[idx] = inc - deg[idx];
        }
    }
    if (b == 0 && t == 0) row_off[0] = 0;
}

// -------- fill: esrc[pos] = src, 4 edges/thread (pipelined atomics) --------
__global__ __launch_bounds__(256) void fill_kernel(const int* __restrict__ src,
                                                   const int* __restrict__ dst,
                                                   int* __restrict__ cursor,
                                                   int* __restrict__ esrc) {
    const int base = blockIdx.x * 1024 + threadIdx.x;
    int d0 = dst[base];
    int d1 = dst[base + 256];
    int d2 = dst[base + 512];
    int d3 = dst[base + 768];
    int s0 = src[base];
    int s1 = src[base + 256];
    int s2 = src[base + 512];
    int s3 = src[base + 768];
    int p0 = atomicAdd(&cursor[d0], 1);
    int p1 = atomicAdd(&cursor[d1], 1);
    int p2 = atomicAdd(&cursor[d2], 1);
    int p3 = atomicAdd(&cursor[d3], 1);
    esrc[p0] = s0;
    esrc[p1] = s1;
    esrc[p2] = s2;
    esrc[p3] = s3;
}

// -------- gather + mean (bf16): one wave per node, 4 edges per load instr --------
// lane = g*16 + c : edge-slot g (0..3), 16B chunk c (0..15) of the 256B row.
__global__ __launch_bounds__(256) void gather_mean(const int* __restrict__ row_off,
                                                   const int* __restrict__ esrc,
                                                   const ushort* __restrict__ feat,
                                                   ushort* __restrict__ mean) {
    const int node = (blockIdx.x * 256 + threadIdx.x) >> 6;
    const int lane = threadIdx.x & 63;
    if (node >= N_NODES) return;
    const int beg = row_off[node];
    const int end = row_off[node + 1];
    const int g = lane >> 4;           // edge sub-slot
    const int c = lane & 15;           // 16B chunk
    const char* fb = (const char*)feat;
    float acc[8];
#pragma unroll
    for (int r = 0; r < 8; ++r) acc[r] = 0.0f;

    for (int i = beg; i < end; i += 8) {
        int i0 = i + g;
        int i1 = i + 4 + g;
        uint4 v0 = make_uint4(0u, 0u, 0u, 0u);
        uint4 v1 = make_uint4(0u, 0u, 0u, 0u);
        if (i0 < end) {
            int s = esrc[i0];
            v0 = *(const uint4*)(fb + ((size_t)s << 8) + c * 16);
        }
        if (i1 < end) {
            int s = esrc[i1];
            v1 = *(const uint4*)(fb + ((size_t)s << 8) + c * 16);
        }
        acc[0] += bflo(v0.x) + bflo(v1.x);
        acc[1] += bfhi(v0.x) + bfhi(v1.x);
        acc[2] += bflo(v0.y) + bflo(v1.y);
        acc[3] += bfhi(v0.y) + bfhi(v1.y);
        acc[4] += bflo(v0.z) + bflo(v1.z);
        acc[5] += bfhi(v0.z) + bfhi(v1.z);
        acc[6] += bflo(v0.w) + bflo(v1.w);
        acc[7] += bfhi(v0.w) + bfhi(v1.w);
    }
    // reduce across the 4 edge-slots (lane bits 4,5)
#pragma unroll
    for (int r = 0; r < 8; ++r) {
        acc[r] += __shfl_xor(acc[r], 16, 64);
        acc[r] += __shfl_xor(acc[r], 32, 64);
    }
    if (g == 0) {
        const int dg = end - beg;
        const float inv = (dg > 0) ? 1.0f / (float)dg : 0.0f;
        union { ushort u[8]; uint4 v; } p;
#pragma unroll
        for (int r = 0; r < 8; ++r) p.u[r] = f2bf(acc[r] * inv);
        *(uint4*)((char*)mean + ((size_t)node << 8) + c * 16) = p.v;
    }
}

// -------- fused MFMA: out = relu( [mean|feat](bf16) @ Wb^T + b ) --------
// Block: 256 threads (4 waves), tile 64 nodes x 128 outs, K = 256.
// Wave w owns cols [w*32, w*32+32): acc[4 mfrag][2 nfrag].
// A staged in LDS bf16, XOR-swizzled: byte ^= (row&7)<<4.
template <int OUT_BF16>
__global__ __launch_bounds__(256) void sage_mfma(const ushort* __restrict__ feat,
                                                 const ushort* __restrict__ mean,
                                                 const ushort* __restrict__ Wb,
                                                 const float* __restrict__ bias,
                                                 void* __restrict__ outv) {
    __shared__ __align__(16) char As[64 * 512];   // 64 rows x 256 bf16, swizzled

    const int tid = threadIdx.x;
    const int nodeBase = blockIdx.x * 64;

    // ---- stage: bf16 rows -> swizzled LDS ----
    {
        const int row = tid >> 2;          // 0..63
        const int q = tid & 3;             // 128-byte quarter of the 512B row
        const int node = nodeBase + row;
        const bool valid = node < N_NODES;
        const ushort* srcp = (q < 2) ? (mean + (size_t)node * D + q * 64)
                                     : (feat + (size_t)node * D + (q - 2) * 64);
        const int swz = (row & 7) << 4;
#pragma unroll
        for (int c = 0; c < 8; ++c) {      // 8 chunks of 16 B
            uint4 v = make_uint4(0u, 0u, 0u, 0u);
            if (valid) v = *(const uint4*)(srcp + c * 8);
            int colb = q * 128 + c * 16;   // byte col
            *(uint4*)(As + row * 512 + (colb ^ swz)) = v;
        }
    }
    __syncthreads();

    // ---- MFMA main loop ----
    const int lane = tid & 63;
    const int w = tid >> 6;            // wave id: col slice w*32
    const int l15 = lane & 15;
    const int lg = lane >> 4;          // k-group
    const int swz = (l15 & 7) << 4;

    f32x4 acc[4][2];
#pragma unroll
    for (int m = 0; m < 4; ++m) {
        acc[m][0] = (f32x4)(0.0f);
        acc[m][1] = (f32x4)(0.0f);
    }

    const ushort* WA = Wb + (size_t)(w * 32 + l15) * 256 + lg * 8;
    const ushort* WB = WA + 16 * 256;

#pragma unroll
    for (int t = 0; t < 8; ++t) {      // k0 = t*32
        bf16x8 b0 = *(const bf16x8*)(WA + t * 32);
        bf16x8 b1 = *(const bf16x8*)(WB + t * 32);
        const int kb = t * 64 + lg * 16;                   // byte col base
#pragma unroll
        for (int m = 0; m < 4; ++m) {
            bf16x8 a = *(const bf16x8*)(As + (m * 16 + l15) * 512 + (kb ^ swz));
            acc[m][0] = __builtin_amdgcn_mfma_f32_16x16x32_bf16(a, b0, acc[m][0], 0, 0, 0);
            acc[m][1] = __builtin_amdgcn_mfma_f32_16x16x32_bf16(a, b1, acc[m][1], 0, 0, 0);
        }
    }

    // ---- epilogue: bias + relu + store ----
    const int c0 = w * 32 + l15;
    const float bv0 = bias[c0];
    const float bv1 = bias[c0 + 16];
#pragma unroll
    for (int m = 0; m < 4; ++m) {
#pragma unroll
        for (int j = 0; j < 4; ++j) {
            int node = nodeBase + m * 16 + lg * 4 + j;
            if (node < N_NODES) {
                float r0 = fmaxf(acc[m][0][j] + bv0, 0.0f);
                float r1 = fmaxf(acc[m][1][j] + bv1, 0.0f);
                if (OUT_BF16) {
                    ushort* out = (ushort*)outv;
                    out[(size_t)node * D + c0]      = f2bf(r0);
                    out[(size_t)node * D + c0 + 16] = f2bf(r1);
                } else {
                    float* out = (float*)outv;
                    out[(size_t)node * D + c0]      = r0;
                    out[(size_t)node * D + c0 + 16] = r1;
                }
            }
        }
    }
}

extern "C" void kernel_launch(void* const* d_in, const int* in_sizes, int n_in,
                              void* d_out, int out_size, void* d_ws, size_t ws_size,
                              hipStream_t stream) {
    const float* x   = (const float*)d_in[0];
    const int*   ei  = (const int*)d_in[1];   // jax x64 disabled -> int32
    const int*   src = ei;
    const int*   dst = ei + N_EDGES;
    const float* W1l = (const float*)d_in[2];
    const float* b1  = (const float*)d_in[3];
    const float* W1r = (const float*)d_in[4];
    const float* W2l = (const float*)d_in[5];
    const float* b2  = (const float*)d_in[6];
    const float* W2r = (const float*)d_in[7];
    float* out = (float*)d_out;

    ushort* xb     = (ushort*)d_ws;                        // N*D bf16
    ushort* hb     = xb + (size_t)N_NODES * D;             // N*D bf16
    ushort* meanb  = hb + (size_t)N_NODES * D;             // N*D bf16
    int*   row_off = (int*)(meanb + (size_t)N_NODES * D);  // N+1
    int*   cursor  = row_off + (N_NODES + 1);              // N
    int*   esrc    = cursor + N_NODES;                     // E
    int*   deg     = esrc + N_EDGES;                       // N
    int*   incl    = deg + N_NODES;                        // N
    int*   blockSum= incl + N_NODES;                       // SCAN_BLK
    ushort* Wb1    = (ushort*)(blockSum + SCAN_BLK);       // 128*256 bf16
    ushort* Wb2    = Wb1 + 128 * 256;                      // 128*256 bf16

    const int edge4Blocks = N_EDGES / 1024;                // 625 exact
    const int waveBlocks = (N_NODES * 64 + 255) / 256;     // 12500
    const int gemmBlocks = (N_NODES + 63) / 64;            // 782
    const int prepBlocks = 3125 + 256 + (N_NODES + 255) / 256;  // 3577

    // ---- prep + CSR build (once; shared by both layers) ----
    prep_kernel<<<prepBlocks, 256, 0, stream>>>(x, W1l, W1r, W2l, W2r, xb, Wb1, Wb2, deg);
    hist_kernel<<<edge4Blocks, 256, 0, stream>>>(dst, deg);
    scan1_kernel<<<SCAN_BLK, 256, 0, stream>>>(deg, incl, blockSum);
    scan2_kernel<<<SCAN_BLK, 256, 0, stream>>>(deg, incl, blockSum, row_off, cursor);
    fill_kernel<<<edge4Blocks, 256, 0, stream>>>(src, dst, cursor, esrc);

    // ---- layer 1 ----
    gather_mean<<<waveBlocks, 256, 0, stream>>>(row_off, esrc, xb, meanb);
    sage_mfma<1><<<gemmBlocks, 256, 0, stream>>>(xb, meanb, Wb1, b1, hb);

    // ---- layer 2 ----
    gather_mean<<<waveBlocks, 256, 0, stream>>>(row_off, esrc, hb, meanb);
    sage_mfma<0><<<gemmBlocks, 256, 0, stream>>>(hb, meanb, Wb2, b2, out);
}